// Round 1
// baseline (274.636 us; speedup 1.0000x reference)
//
#include <hip/hip_runtime.h>
#include <stdint.h>

// ---------------------------------------------------------------------------
// SingleHeadedAttention (Mega-style, laplacian attn fn, causal, T5 rel bias)
// B=4, S=2048, DIM=1024, DQK=128, DV=1024.  fp32 in/out, bf16 MFMA internals.
// Pipeline: convert/transposes -> gemm_qk -> gemm_v -> transpose_v ->
//           gemm_sim (epilogue: bias+erf+mask -> attn bf16) -> gemm_out.
// All GEMMs are C = A * B^T with A,[B^T] row-major [.][K], bf16, MFMA
// 16x16x32, 128x128 block tile, BK=32, 4 waves of 2x2x(4x4) 16x16 tiles.
// ---------------------------------------------------------------------------

#define B_   4
#define S_   2048
#define DIM_ 1024
#define DQK  128
#define DV   1024

typedef __attribute__((ext_vector_type(8))) short short8;   // 8 bf16 (4 VGPRs)
typedef __attribute__((ext_vector_type(4))) float f32x4;    // MFMA C/D

__device__ __forceinline__ uint16_t f32_to_bf16(float f) {
  uint32_t u = __float_as_uint(f);
  u += 0x7FFFu + ((u >> 16) & 1u);          // round-to-nearest-even
  return (uint16_t)(u >> 16);
}

__device__ __forceinline__ float silu_f(float x) {
  return x / (1.0f + expf(-x));
}

__device__ __forceinline__ float laplacian_attn(float x) {
  // (1 + erf((x - sqrt(0.5)) / sqrt(0.5*pi))) * 0.5
  return 0.5f * (1.0f + erff((x - 0.70710678118654752f) * 0.79788456080286536f));
}

// ---- core: 128x128 output tile, C = A(rows i0..) * Bt(rows n0..)^T --------
// A: [M][lda] bf16 row-major, Bt: [N][ldb] bf16 row-major (i.e. B^T), k-contig.
// K must be a multiple of 32. Tiles always full (no bounds checks).
__device__ __forceinline__ void gemm128_core(
    const uint16_t* __restrict__ A, int lda,
    const uint16_t* __restrict__ Bt, int ldb,
    long i0, long n0, int K, f32x4 acc[4][4])
{
  __shared__ uint16_t lAs[128 * 40];   // 32 cols padded to 40 (80B rows)
  __shared__ uint16_t lBs[128 * 40];

  const int t      = threadIdx.x;          // 0..255
  const int lane   = t & 63;
  const int wave   = t >> 6;
  const int lane16 = lane & 15;
  const int quad   = lane >> 4;
  const int wr     = (wave >> 1) * 64;     // wave row offset in 128-tile
  const int wc     = (wave & 1) * 64;      // wave col offset

  #pragma unroll
  for (int mt = 0; mt < 4; mt++)
    #pragma unroll
    for (int nt = 0; nt < 4; nt++) {
      f32x4 z = {0.0f, 0.0f, 0.0f, 0.0f};
      acc[mt][nt] = z;
    }

  const int row_s = t >> 2;                // 0..63, +64 for second pass
  const int col8  = (t & 3) << 3;          // {0,8,16,24}

  for (int k0 = 0; k0 < K; k0 += 32) {
    __syncthreads();
    #pragma unroll
    for (int p = 0; p < 2; p++) {
      int row = row_s + p * 64;
      *(float4*)&lAs[row * 40 + col8] =
          *(const float4*)&A[(i0 + row) * (long)lda + k0 + col8];
      *(float4*)&lBs[row * 40 + col8] =
          *(const float4*)&Bt[(n0 + row) * (long)ldb + k0 + col8];
    }
    __syncthreads();

    short8 af[4], bfr[4];
    #pragma unroll
    for (int mt = 0; mt < 4; mt++)
      af[mt] = *(const short8*)&lAs[(wr + mt * 16 + lane16) * 40 + quad * 8];
    #pragma unroll
    for (int nt = 0; nt < 4; nt++)
      bfr[nt] = *(const short8*)&lBs[(wc + nt * 16 + lane16) * 40 + quad * 8];

    #pragma unroll
    for (int mt = 0; mt < 4; mt++)
      #pragma unroll
      for (int nt = 0; nt < 4; nt++)
        acc[mt][nt] = __builtin_amdgcn_mfma_f32_16x16x32_bf16(
            af[mt], bfr[nt], acc[mt][nt], 0, 0, 0);
  }
}

// epilogue index helpers: row = wr + mt*16 + quad*4 + r ; col = wc + nt*16 + lane16
#define EPI_PREAMBLE                                   \
  int lane = threadIdx.x & 63;                         \
  int wave = threadIdx.x >> 6;                         \
  int lane16 = lane & 15;                              \
  int quad = lane >> 4;                                \
  int wr = (wave >> 1) * 64;                           \
  int wc = (wave & 1) * 64;

// ---- prep kernels ----------------------------------------------------------

__global__ __launch_bounds__(256) void k_convert_x(
    const float* __restrict__ in, uint16_t* __restrict__ out, int n4)
{
  int i = blockIdx.x * blockDim.x + threadIdx.x;
  if (i >= n4) return;
  float4 v = ((const float4*)in)[i];
  ushort4 o;
  o.x = f32_to_bf16(v.x); o.y = f32_to_bf16(v.y);
  o.z = f32_to_bf16(v.z); o.w = f32_to_bf16(v.w);
  ((ushort4*)out)[i] = o;
}

// in: fp32 [R][C]  ->  out: bf16 [C][R]   (R, C multiples of 32), block (32,8)
__global__ __launch_bounds__(256) void k_transpose_f32_bf16(
    const float* __restrict__ in, uint16_t* __restrict__ out, int R, int C)
{
  __shared__ float tile[32][33];
  int c0 = blockIdx.x * 32, r0 = blockIdx.y * 32;
  int tx = threadIdx.x, ty = threadIdx.y;
  #pragma unroll
  for (int k = 0; k < 32; k += 8)
    tile[ty + k][tx] = in[(long)(r0 + ty + k) * C + c0 + tx];
  __syncthreads();
  #pragma unroll
  for (int k = 0; k < 32; k += 8)
    out[(long)(c0 + ty + k) * R + r0 + tx] = f32_to_bf16(tile[tx][ty + k]);
}

// v bf16 [B*S][DV] -> vT bf16 [B][DV][S], block (32,8), grid (DV/32, S/32, B)
__global__ __launch_bounds__(256) void k_transpose_v(
    const uint16_t* __restrict__ v, uint16_t* __restrict__ vT)
{
  __shared__ uint16_t tile[32][33];
  int b = blockIdx.z;
  int n0 = blockIdx.x * 32, j0 = blockIdx.y * 32;
  int tx = threadIdx.x, ty = threadIdx.y;
  #pragma unroll
  for (int k = 0; k < 32; k += 8)
    tile[ty + k][tx] = v[((long)b * S_ + j0 + ty + k) * DV + n0 + tx];
  __syncthreads();
  #pragma unroll
  for (int k = 0; k < 32; k += 8)
    vT[((long)b * DV + n0 + ty + k) * S_ + j0 + tx] = tile[tx][ty + k];
}

// bias_n[n] = rel_bias[bucket(n)] * sqrt(DQK), n = i - j in [0, S)
__global__ __launch_bounds__(256) void k_bias(
    const float* __restrict__ rel, float* __restrict__ bias_n)
{
  int n = blockIdx.x * blockDim.x + threadIdx.x;
  if (n >= S_) return;
  int bucket;
  if (n < 16) {
    bucket = n;
  } else {
    // matches jax fp32: log(n/16) / fp32(log(8)) * 16, truncate, clamp 31
    float tt = logf((float)n * 0.0625f) / 2.0794415416798357f * 16.0f;
    int vl = 16 + (int)tt;
    bucket = vl < 31 ? vl : 31;
  }
  bias_n[n] = rel[bucket] * 11.313708498984761f;   // * sqrt(128)
}

// ---- GEMM kernels ----------------------------------------------------------

// qk = silu(x@wqk + bqk); q = qk*g0+b0, k = qk*g1+b1  (bf16 outs, [B*S][DQK])
__global__ __launch_bounds__(256) void k_gemm_qk(
    const uint16_t* __restrict__ xb, const uint16_t* __restrict__ wqkT,
    const float* __restrict__ bqk, const float* __restrict__ gamma,
    const float* __restrict__ beta,
    uint16_t* __restrict__ qb, uint16_t* __restrict__ kb)
{
  long i0 = (long)blockIdx.x * 128;
  f32x4 acc[4][4];
  gemm128_core(xb, DIM_, wqkT, DIM_, i0, 0, DIM_, acc);
  EPI_PREAMBLE
  #pragma unroll
  for (int mt = 0; mt < 4; mt++)
    #pragma unroll
    for (int nt = 0; nt < 4; nt++)
      #pragma unroll
      for (int r = 0; r < 4; r++) {
        int row = wr + mt * 16 + quad * 4 + r;
        int col = wc + nt * 16 + lane16;       // 0..127 = DQK
        float vsum = acc[mt][nt][r] + bqk[col];
        float s = silu_f(vsum);
        float qv = s * gamma[col] + beta[col];
        float kv = s * gamma[DQK + col] + beta[DQK + col];
        qb[(i0 + row) * DQK + col] = f32_to_bf16(qv);
        kb[(i0 + row) * DQK + col] = f32_to_bf16(kv);
      }
}

// v = silu(x@wv + bv)  (bf16 out [B*S][DV])
__global__ __launch_bounds__(256) void k_gemm_v(
    const uint16_t* __restrict__ xb, const uint16_t* __restrict__ wvT,
    const float* __restrict__ bv, uint16_t* __restrict__ vb)
{
  long i0 = (long)blockIdx.y * 128;
  long n0 = (long)blockIdx.x * 128;
  f32x4 acc[4][4];
  gemm128_core(xb, DIM_, wvT, DIM_, i0, n0, DIM_, acc);
  EPI_PREAMBLE
  #pragma unroll
  for (int mt = 0; mt < 4; mt++)
    #pragma unroll
    for (int nt = 0; nt < 4; nt++)
      #pragma unroll
      for (int r = 0; r < 4; r++) {
        int row = wr + mt * 16 + quad * 4 + r;
        long gc = n0 + wc + nt * 16 + lane16;
        float vsum = acc[mt][nt][r] + bv[gc];
        vb[(i0 + row) * DV + gc] = f32_to_bf16(silu_f(vsum));
      }
}

// attn = laplacian(q@k^T / S + bias[i-j]) masked causal, bf16 [B][S][S]
// grid (S/128 jt, S/128 it, B); upper-triangle blocks skipped (never read)
__global__ __launch_bounds__(256) void k_gemm_sim(
    const uint16_t* __restrict__ qb, const uint16_t* __restrict__ kb,
    const float* __restrict__ bias_n, uint16_t* __restrict__ attn)
{
  int bt = blockIdx.z;
  int it = blockIdx.y, jt = blockIdx.x;
  if (jt > it) return;
  long i0 = (long)it * 128, j0 = (long)jt * 128;
  const uint16_t* q = qb + (long)bt * S_ * DQK;
  const uint16_t* k = kb + (long)bt * S_ * DQK;
  f32x4 acc[4][4];
  gemm128_core(q, DQK, k, DQK, i0, j0, DQK, acc);
  uint16_t* ab = attn + (long)bt * S_ * S_;
  EPI_PREAMBLE
  #pragma unroll
  for (int mt = 0; mt < 4; mt++)
    #pragma unroll
    for (int nt = 0; nt < 4; nt++)
      #pragma unroll
      for (int r = 0; r < 4; r++) {
        long i = i0 + wr + mt * 16 + quad * 4 + r;
        long j = j0 + wc + nt * 16 + lane16;
        float aval = 0.0f;
        if (j <= i) {
          float sim = acc[mt][nt][r] * (1.0f / 2048.0f) + bias_n[i - j];
          aval = laplacian_attn(sim);
        }
        ab[i * S_ + j] = f32_to_bf16(aval);
      }
}

// out = attn @ v  (fp32 out), K bounded causally at i0+128; big tiles first
__global__ __launch_bounds__(256) void k_gemm_out(
    const uint16_t* __restrict__ attn, const uint16_t* __restrict__ vT,
    float* __restrict__ out)
{
  int bt = blockIdx.z;
  int it = (int)gridDim.y - 1 - (int)blockIdx.y;   // launch big-K tiles first
  long i0 = (long)it * 128;
  long n0 = (long)blockIdx.x * 128;
  int K = (int)i0 + 128;                           // j <= i  => k < i0+128
  f32x4 acc[4][4];
  gemm128_core(attn + (long)bt * S_ * S_, S_,
               vT + (long)bt * DV * S_, S_, i0, n0, K, acc);
  EPI_PREAMBLE
  #pragma unroll
  for (int mt = 0; mt < 4; mt++)
    #pragma unroll
    for (int nt = 0; nt < 4; nt++)
      #pragma unroll
      for (int r = 0; r < 4; r++) {
        int row = wr + mt * 16 + quad * 4 + r;
        int col = wc + nt * 16 + lane16;
        out[((long)bt * S_ + i0 + row) * DV + n0 + col] = acc[mt][nt][r];
      }
}

// ---------------------------------------------------------------------------

extern "C" void kernel_launch(void* const* d_in, const int* in_sizes, int n_in,
                              void* d_out, int out_size, void* d_ws, size_t ws_size,
                              hipStream_t stream)
{
  const float* x     = (const float*)d_in[0];
  const float* wqk   = (const float*)d_in[1];
  const float* bqk   = (const float*)d_in[2];
  const float* gamma = (const float*)d_in[3];
  const float* beta  = (const float*)d_in[4];
  const float* wv    = (const float*)d_in[5];
  const float* bv    = (const float*)d_in[6];
  const float* rel   = (const float*)d_in[7];
  float* out = (float*)d_out;

  char* ws = (char*)d_ws;
  size_t off = 0;
  uint16_t* xb     = (uint16_t*)(ws + off); off += (size_t)B_ * S_ * DIM_ * 2;  // 16 MB
  uint16_t* wqkT   = (uint16_t*)(ws + off); off += (size_t)DQK * DIM_ * 2;      // 256 KB
  uint16_t* wvT    = (uint16_t*)(ws + off); off += (size_t)DV * DIM_ * 2;       // 2 MB
  uint16_t* qb     = (uint16_t*)(ws + off); off += (size_t)B_ * S_ * DQK * 2;   // 2 MB
  uint16_t* kb     = (uint16_t*)(ws + off); off += (size_t)B_ * S_ * DQK * 2;   // 2 MB
  uint16_t* vb     = (uint16_t*)(ws + off); off += (size_t)B_ * S_ * DV * 2;    // 16 MB
  uint16_t* vT     = (uint16_t*)(ws + off); off += (size_t)B_ * DV * S_ * 2;    // 16 MB
  uint16_t* attn   = (uint16_t*)(ws + off); off += (size_t)B_ * S_ * S_ * 2;    // 32 MB
  float*    bias_n = (float*)(ws + off);    off += (size_t)S_ * 4;              // 8 KB
  // total ~90.5 MB of d_ws

  const int n_x = B_ * S_ * DIM_;
  k_convert_x<<<dim3((n_x / 4 + 255) / 256), dim3(256), 0, stream>>>(x, xb, n_x / 4);
  k_transpose_f32_bf16<<<dim3(DQK / 32, DIM_ / 32), dim3(32, 8), 0, stream>>>(wqk, wqkT, DIM_, DQK);
  k_transpose_f32_bf16<<<dim3(DV / 32, DIM_ / 32), dim3(32, 8), 0, stream>>>(wv, wvT, DIM_, DV);
  k_bias<<<dim3(S_ / 256), dim3(256), 0, stream>>>(rel, bias_n);

  k_gemm_qk<<<dim3(B_ * S_ / 128), dim3(256), 0, stream>>>(xb, wqkT, bqk, gamma, beta, qb, kb);
  k_gemm_v<<<dim3(DV / 128, B_ * S_ / 128), dim3(256), 0, stream>>>(xb, wvT, bv, vb);
  k_transpose_v<<<dim3(DV / 32, S_ / 32, B_), dim3(32, 8), 0, stream>>>(vb, vT);
  k_gemm_sim<<<dim3(S_ / 128, S_ / 128, B_), dim3(256), 0, stream>>>(qb, kb, bias_n, attn);
  k_gemm_out<<<dim3(DV / 128, S_ / 128, B_), dim3(256), 0, stream>>>(attn, vT, out);
}

// Round 2
// 258.083 us; speedup vs baseline: 1.0641x; 1.0641x over previous
//
#include <hip/hip_runtime.h>
#include <stdint.h>

// ---------------------------------------------------------------------------
// SingleHeadedAttention (Mega-style, laplacian attn fn, causal, T5 rel bias)
// B=4, S=2048, DIM=1024, DQK=128, DV=1024.  fp32 in/out, bf16 MFMA internals.
// R1: global_load_lds(16B) staging, unpadded LDS (conflict-free frag reads),
//     fused qk+v projection GEMM (concat weights, N=1152), balanced causal
//     scheduling for attn@v.
// ---------------------------------------------------------------------------

#define B_   4
#define S_   2048
#define DIM_ 1024
#define DQK  128
#define DV   1024
#define NQV  (DQK + DV)   // 1152

typedef __attribute__((ext_vector_type(8))) short short8;   // 8 bf16 (4 VGPRs)
typedef __attribute__((ext_vector_type(4))) float f32x4;    // MFMA C/D

__device__ __forceinline__ uint16_t f32_to_bf16(float f) {
  uint32_t u = __float_as_uint(f);
  u += 0x7FFFu + ((u >> 16) & 1u);          // round-to-nearest-even
  return (uint16_t)(u >> 16);
}

__device__ __forceinline__ float silu_f(float x) {
  return x / (1.0f + expf(-x));
}

__device__ __forceinline__ float laplacian_attn(float x) {
  // (1 + erf((x - sqrt(0.5)) / sqrt(0.5*pi))) * 0.5
  return 0.5f * (1.0f + erff((x - 0.70710678118654752f) * 0.79788456080286536f));
}

// async 16B global->LDS (lands at lds_base + lane*16)
__device__ __forceinline__ void async_ld16(const void* g, void* l) {
  __builtin_amdgcn_global_load_lds(
      (const __attribute__((address_space(1))) void*)g,
      (__attribute__((address_space(3))) void*)l, 16, 0, 0);
}

// ---- core: 128x128 output tile, C = A(rows i0..) * Bt(rows n0..)^T --------
// A: [M][lda] bf16 row-major, Bt: [N][ldb] bf16 row-major (i.e. B^T), k-contig.
// K multiple of 32; rows 16B-aligned. Unpadded LDS: 128 rows x 32 cols (64B).
// Staging: wave w, insn m in {0,1}: rows w*32+m*16 .. +15, lane l covers
// row base+(l>>2), col elems (l&3)*8 — lds dst base + l*16 matches exactly.
__device__ __forceinline__ void gemm128_core(
    const uint16_t* __restrict__ A, int lda,
    const uint16_t* __restrict__ Bt, int ldb,
    long i0, long n0, int K, f32x4 acc[4][4])
{
  __shared__ uint16_t lAs[128 * 32];
  __shared__ uint16_t lBs[128 * 32];

  const int t      = threadIdx.x;          // 0..255
  const int lane   = t & 63;
  const int wave   = t >> 6;
  const int lane16 = lane & 15;
  const int quad   = lane >> 4;
  const int wr     = (wave >> 1) * 64;     // wave row offset in 128-tile
  const int wc     = (wave & 1) * 64;      // wave col offset

  #pragma unroll
  for (int mt = 0; mt < 4; mt++)
    #pragma unroll
    for (int nt = 0; nt < 4; nt++) {
      f32x4 z = {0.0f, 0.0f, 0.0f, 0.0f};
      acc[mt][nt] = z;
    }

  const int srow = wave * 32 + (lane >> 2);    // + m*16
  const int scol = (lane & 3) * 8;             // element offset in k
  const uint16_t* gA = A  + (i0 + srow) * (long)lda + scol;
  const uint16_t* gB = Bt + (n0 + srow) * (long)ldb + scol;
  uint16_t* lA = &lAs[(wave * 32) * 32];
  uint16_t* lB = &lBs[(wave * 32) * 32];

  for (int k0 = 0; k0 < K; k0 += 32) {
    __syncthreads();                          // prev MFMA reads done
    #pragma unroll
    for (int m = 0; m < 2; m++) {
      async_ld16(gA + (long)m * 16 * lda + k0, lA + m * 16 * 32);
      async_ld16(gB + (long)m * 16 * ldb + k0, lB + m * 16 * 32);
    }
    __syncthreads();                          // drains vmcnt + barrier

    short8 af[4], bfr[4];
    #pragma unroll
    for (int mt = 0; mt < 4; mt++)
      af[mt] = *(const short8*)&lAs[(wr + mt * 16 + lane16) * 32 + quad * 8];
    #pragma unroll
    for (int nt = 0; nt < 4; nt++)
      bfr[nt] = *(const short8*)&lBs[(wc + nt * 16 + lane16) * 32 + quad * 8];

    #pragma unroll
    for (int mt = 0; mt < 4; mt++)
      #pragma unroll
      for (int nt = 0; nt < 4; nt++)
        acc[mt][nt] = __builtin_amdgcn_mfma_f32_16x16x32_bf16(
            af[mt], bfr[nt], acc[mt][nt], 0, 0, 0);
  }
}

// epilogue index helpers: row = wr + mt*16 + quad*4 + r ; col = wc + nt*16 + lane16
#define EPI_PREAMBLE                                   \
  int lane = threadIdx.x & 63;                         \
  int wave = threadIdx.x >> 6;                         \
  int lane16 = lane & 15;                              \
  int quad = lane >> 4;                                \
  int wr = (wave >> 1) * 64;                           \
  int wc = (wave & 1) * 64;

// ---- prep kernels ----------------------------------------------------------

__global__ __launch_bounds__(256) void k_convert_x(
    const float* __restrict__ in, uint16_t* __restrict__ out, int n4)
{
  int i = blockIdx.x * blockDim.x + threadIdx.x;
  if (i >= n4) return;
  float4 v = ((const float4*)in)[i];
  ushort4 o;
  o.x = f32_to_bf16(v.x); o.y = f32_to_bf16(v.y);
  o.z = f32_to_bf16(v.z); o.w = f32_to_bf16(v.w);
  ((ushort4*)out)[i] = o;
}

// in: fp32 [R][C] -> out: bf16 [C][R]  (R,C mult of 32), block (32,8)
__global__ __launch_bounds__(256) void k_transpose_f32_bf16(
    const float* __restrict__ in, uint16_t* __restrict__ out, int R, int C)
{
  __shared__ float tile[32][33];
  int c0 = blockIdx.x * 32, r0 = blockIdx.y * 32;
  int tx = threadIdx.x, ty = threadIdx.y;
  #pragma unroll
  for (int k = 0; k < 32; k += 8)
    tile[ty + k][tx] = in[(long)(r0 + ty + k) * C + c0 + tx];
  __syncthreads();
  #pragma unroll
  for (int k = 0; k < 32; k += 8)
    out[(long)(c0 + ty + k) * R + r0 + tx] = f32_to_bf16(tile[tx][ty + k]);
}

// v bf16 [B*S][DV] -> vT bf16 [B][DV][S], block (32,8), grid (DV/32, S/32, B)
__global__ __launch_bounds__(256) void k_transpose_v(
    const uint16_t* __restrict__ v, uint16_t* __restrict__ vT)
{
  __shared__ uint16_t tile[32][33];
  int b = blockIdx.z;
  int n0 = blockIdx.x * 32, j0 = blockIdx.y * 32;
  int tx = threadIdx.x, ty = threadIdx.y;
  #pragma unroll
  for (int k = 0; k < 32; k += 8)
    tile[ty + k][tx] = v[((long)b * S_ + j0 + ty + k) * DV + n0 + tx];
  __syncthreads();
  #pragma unroll
  for (int k = 0; k < 32; k += 8)
    vT[((long)b * DV + n0 + ty + k) * S_ + j0 + tx] = tile[tx][ty + k];
}

// bias_n[n] = rel_bias[bucket(n)] * sqrt(DQK), n = i - j in [0, S)
__global__ __launch_bounds__(256) void k_bias(
    const float* __restrict__ rel, float* __restrict__ bias_n)
{
  int n = blockIdx.x * blockDim.x + threadIdx.x;
  if (n >= S_) return;
  int bucket;
  if (n < 16) {
    bucket = n;
  } else {
    float tt = logf((float)n * 0.0625f) / 2.0794415416798357f * 16.0f;
    int vl = 16 + (int)tt;
    bucket = vl < 31 ? vl : 31;
  }
  bias_n[n] = rel[bucket] * 11.313708498984761f;   // * sqrt(128)
}

// ---- GEMM kernels ----------------------------------------------------------

// fused projections: n0==0 tile -> q/k epilogue; n0>=128 -> v epilogue.
// wT: [NQV][DIM] bf16 (rows 0..127 = wqk^T, 128..1151 = wv^T)
__global__ __launch_bounds__(256) void k_gemm_qkv(
    const uint16_t* __restrict__ xb, const uint16_t* __restrict__ wT,
    const float* __restrict__ bqk, const float* __restrict__ gamma,
    const float* __restrict__ beta, const float* __restrict__ bv,
    uint16_t* __restrict__ qb, uint16_t* __restrict__ kb,
    uint16_t* __restrict__ vb)
{
  long i0 = (long)blockIdx.y * 128;
  long n0 = (long)blockIdx.x * 128;
  f32x4 acc[4][4];
  gemm128_core(xb, DIM_, wT, DIM_, i0, n0, DIM_, acc);
  EPI_PREAMBLE
  if (n0 == 0) {
    #pragma unroll
    for (int mt = 0; mt < 4; mt++)
      #pragma unroll
      for (int nt = 0; nt < 4; nt++)
        #pragma unroll
        for (int r = 0; r < 4; r++) {
          int row = wr + mt * 16 + quad * 4 + r;
          int col = wc + nt * 16 + lane16;           // 0..127 = DQK
          float vsum = acc[mt][nt][r] + bqk[col];
          float s = silu_f(vsum);
          float qv = s * gamma[col] + beta[col];
          float kv = s * gamma[DQK + col] + beta[DQK + col];
          qb[(i0 + row) * DQK + col] = f32_to_bf16(qv);
          kb[(i0 + row) * DQK + col] = f32_to_bf16(kv);
        }
  } else {
    long v0 = n0 - DQK;
    #pragma unroll
    for (int mt = 0; mt < 4; mt++)
      #pragma unroll
      for (int nt = 0; nt < 4; nt++)
        #pragma unroll
        for (int r = 0; r < 4; r++) {
          int row = wr + mt * 16 + quad * 4 + r;
          long gc = v0 + wc + nt * 16 + lane16;
          float vsum = acc[mt][nt][r] + bv[gc];
          vb[(i0 + row) * DV + gc] = f32_to_bf16(silu_f(vsum));
        }
  }
}

// attn = laplacian(q@k^T / S + bias[i-j]) masked causal, bf16 [B][S][S]
// grid (S/128 jt, S/128 it, B); upper-triangle blocks skipped (never read)
__global__ __launch_bounds__(256) void k_gemm_sim(
    const uint16_t* __restrict__ qb, const uint16_t* __restrict__ kb,
    const float* __restrict__ bias_n, uint16_t* __restrict__ attn)
{
  int bt = blockIdx.z;
  int it = blockIdx.y, jt = blockIdx.x;
  if (jt > it) return;
  long i0 = (long)it * 128, j0 = (long)jt * 128;
  const uint16_t* q = qb + (long)bt * S_ * DQK;
  const uint16_t* k = kb + (long)bt * S_ * DQK;
  f32x4 acc[4][4];
  gemm128_core(q, DQK, k, DQK, i0, j0, DQK, acc);
  uint16_t* ab = attn + (long)bt * S_ * S_;
  EPI_PREAMBLE
  #pragma unroll
  for (int mt = 0; mt < 4; mt++)
    #pragma unroll
    for (int nt = 0; nt < 4; nt++)
      #pragma unroll
      for (int r = 0; r < 4; r++) {
        long i = i0 + wr + mt * 16 + quad * 4 + r;
        long j = j0 + wc + nt * 16 + lane16;
        float aval = 0.0f;
        if (j <= i) {
          float sim = acc[mt][nt][r] * (1.0f / 2048.0f) + bias_n[i - j];
          aval = laplacian_attn(sim);
        }
        ab[i * S_ + j] = f32_to_bf16(aval);
      }
}

// out = attn @ v (fp32 out), K causally bounded at i0+128.
// grid (DV/128, 64): y encodes (b,t); it chosen so the co-resident pair
// (block c, block c+256) gets K sums ~const: it = (b&2) ? 15-t : t.
__global__ __launch_bounds__(256) void k_gemm_out(
    const uint16_t* __restrict__ attn, const uint16_t* __restrict__ vT,
    float* __restrict__ out)
{
  int y  = blockIdx.y;
  int bt = y >> 4;
  int tt = y & 15;
  int it = (bt & 2) ? (15 - tt) : tt;
  long i0 = (long)it * 128;
  long n0 = (long)blockIdx.x * 128;
  int K = (int)i0 + 128;                           // j <= i  => k < i0+128
  f32x4 acc[4][4];
  gemm128_core(attn + (long)bt * S_ * S_, S_,
               vT + (long)bt * DV * S_, S_, i0, n0, K, acc);
  EPI_PREAMBLE
  #pragma unroll
  for (int mt = 0; mt < 4; mt++)
    #pragma unroll
    for (int nt = 0; nt < 4; nt++)
      #pragma unroll
      for (int r = 0; r < 4; r++) {
        int row = wr + mt * 16 + quad * 4 + r;
        int col = wc + nt * 16 + lane16;
        out[((long)bt * S_ + i0 + row) * DV + n0 + col] = acc[mt][nt][r];
      }
}

// ---------------------------------------------------------------------------

extern "C" void kernel_launch(void* const* d_in, const int* in_sizes, int n_in,
                              void* d_out, int out_size, void* d_ws, size_t ws_size,
                              hipStream_t stream)
{
  const float* x     = (const float*)d_in[0];
  const float* wqk   = (const float*)d_in[1];
  const float* bqk   = (const float*)d_in[2];
  const float* gamma = (const float*)d_in[3];
  const float* beta  = (const float*)d_in[4];
  const float* wv    = (const float*)d_in[5];
  const float* bv    = (const float*)d_in[6];
  const float* rel   = (const float*)d_in[7];
  float* out = (float*)d_out;

  char* ws = (char*)d_ws;
  size_t off = 0;
  uint16_t* xb     = (uint16_t*)(ws + off); off += (size_t)B_ * S_ * DIM_ * 2;  // 16 MB
  uint16_t* wT     = (uint16_t*)(ws + off); off += (size_t)NQV * DIM_ * 2;      // 2.25 MB
  uint16_t* qb     = (uint16_t*)(ws + off); off += (size_t)B_ * S_ * DQK * 2;   // 2 MB
  uint16_t* kb     = (uint16_t*)(ws + off); off += (size_t)B_ * S_ * DQK * 2;   // 2 MB
  uint16_t* vb     = (uint16_t*)(ws + off); off += (size_t)B_ * S_ * DV * 2;    // 16 MB
  uint16_t* vT     = (uint16_t*)(ws + off); off += (size_t)B_ * DV * S_ * 2;    // 16 MB
  uint16_t* attn   = (uint16_t*)(ws + off); off += (size_t)B_ * S_ * S_ * 2;    // 32 MB
  float*    bias_n = (float*)(ws + off);    off += (size_t)S_ * 4;              // 8 KB

  const int n_x = B_ * S_ * DIM_;
  k_convert_x<<<dim3((n_x / 4 + 255) / 256), dim3(256), 0, stream>>>(x, xb, n_x / 4);
  k_transpose_f32_bf16<<<dim3(DQK / 32, DIM_ / 32), dim3(32, 8), 0, stream>>>(wqk, wT, DIM_, DQK);
  k_transpose_f32_bf16<<<dim3(DV / 32, DIM_ / 32), dim3(32, 8), 0, stream>>>(wv, wT + (size_t)DQK * DIM_, DIM_, DV);
  k_bias<<<dim3(S_ / 256), dim3(256), 0, stream>>>(rel, bias_n);

  k_gemm_qkv<<<dim3(NQV / 128, B_ * S_ / 128), dim3(256), 0, stream>>>(
      xb, wT, bqk, gamma, beta, bv, qb, kb, vb);
  k_transpose_v<<<dim3(DV / 32, S_ / 32, B_), dim3(32, 8), 0, stream>>>(vb, vT);
  k_gemm_sim<<<dim3(S_ / 128, S_ / 128, B_), dim3(256), 0, stream>>>(qb, kb, bias_n, attn);
  k_gemm_out<<<dim3(DV / 128, 64), dim3(256), 0, stream>>>(attn, vT, out);
}

// Round 3
// 256.889 us; speedup vs baseline: 1.0691x; 1.0046x over previous
//
#include <hip/hip_runtime.h>
#include <stdint.h>

// ---------------------------------------------------------------------------
// SingleHeadedAttention (Mega-style, laplacian attn fn, causal, T5 rel bias)
// B=4, S=2048, DIM=1024, DQK=128, DV=1024.  fp32 in/out, bf16 MFMA internals.
// R2: depth-2 software-pipelined K-loop — 3-buffer LDS ring, raw s_barrier +
//     explicit s_waitcnt vmcnt(4) via inline asm (no full drain per step).
//     Grids are small (~2 blocks/CU) so intra-block pipelining, not
//     inter-block overlap, must hide the global->LDS latency.
// ---------------------------------------------------------------------------

#define B_   4
#define S_   2048
#define DIM_ 1024
#define DQK  128
#define DV   1024
#define NQV  (DQK + DV)   // 1152

#define NBUF 3            // pipeline depth 2 + 1

typedef __attribute__((ext_vector_type(8))) short short8;   // 8 bf16 (4 VGPRs)
typedef __attribute__((ext_vector_type(4))) float f32x4;    // MFMA C/D

__device__ __forceinline__ uint16_t f32_to_bf16(float f) {
  uint32_t u = __float_as_uint(f);
  u += 0x7FFFu + ((u >> 16) & 1u);          // round-to-nearest-even
  return (uint16_t)(u >> 16);
}

__device__ __forceinline__ float silu_f(float x) {
  return x / (1.0f + expf(-x));
}

__device__ __forceinline__ float laplacian_attn(float x) {
  // (1 + erf((x - sqrt(0.5)) / sqrt(0.5*pi))) * 0.5
  return 0.5f * (1.0f + erff((x - 0.70710678118654752f) * 0.79788456080286536f));
}

// async 16B global->LDS (lands at lds_base + lane*16)
__device__ __forceinline__ void async_ld16(const void* g, void* l) {
  __builtin_amdgcn_global_load_lds(
      (const __attribute__((address_space(1))) void*)g,
      (__attribute__((address_space(3))) void*)l, 16, 0, 0);
}

// stage one 32-wide k-slab for this wave: 4 vmcnt-counted instructions
// (A rows srow, srow+16; B rows srow, srow+16), 16B per lane each.
__device__ __forceinline__ void stage_step(
    const uint16_t* gA, const uint16_t* gB, long lda, long ldb,
    uint16_t* lA, uint16_t* lB)
{
  async_ld16(gA,            lA);
  async_ld16(gA + 16 * lda, lA + 16 * 32);
  async_ld16(gB,            lB);
  async_ld16(gB + 16 * ldb, lB + 16 * 32);
}

// ---- core: 128x128 output tile, C = A(rows i0..) * Bt(rows n0..)^T --------
// A: [M][lda] bf16 row-major, Bt: [N][ldb] bf16 row-major (i.e. B^T), k-contig.
// K multiple of 32; rows 16B-aligned. Unpadded LDS tiles 128x32 per buffer.
// Pipeline (depth 2, 3 buffers): at iter k, tile k is landing (wait vmcnt(4)
// leaves tile k+1 in flight), tile k+2 is issued into tile k-1's buffer.
// Safety: tile k-1's fragments were consumed into VGPRs before barrier(k)
// (lgkm waits precede the MFMAs), and the overwriting DMA needs >=200cyc.
__device__ __forceinline__ void gemm128_core(
    const uint16_t* __restrict__ A, int lda,
    const uint16_t* __restrict__ Bt, int ldb,
    long i0, long n0, int K, f32x4 acc[4][4])
{
  __shared__ uint16_t lAs[NBUF][128 * 32];
  __shared__ uint16_t lBs[NBUF][128 * 32];

  const int t      = threadIdx.x;          // 0..255
  const int lane   = t & 63;
  const int wave   = t >> 6;
  const int lane16 = lane & 15;
  const int quad   = lane >> 4;
  const int wr     = (wave >> 1) * 64;     // wave row offset in 128-tile
  const int wc     = (wave & 1) * 64;      // wave col offset

  #pragma unroll
  for (int mt = 0; mt < 4; mt++)
    #pragma unroll
    for (int nt = 0; nt < 4; nt++) {
      f32x4 z = {0.0f, 0.0f, 0.0f, 0.0f};
      acc[mt][nt] = z;
    }

  // staging geometry: wave w covers rows w*32 .. w*32+31 (two 16-row insns),
  // lane l -> row base+(l>>2), k-elems (l&3)*8 .. +7; LDS dst base + l*16.
  const int srow = wave * 32 + (lane >> 2);
  const int scol = (lane & 3) * 8;
  const uint16_t* gA = A  + (i0 + srow) * (long)lda + scol;
  const uint16_t* gB = Bt + (n0 + srow) * (long)ldb + scol;
  const int lwoff = wave * 32 * 32;        // wave's element offset in a buffer

  const int nsteps = K >> 5;

  // prologue: fill stages 0 and 1
  stage_step(gA, gB, lda, ldb, &lAs[0][lwoff], &lBs[0][lwoff]);
  if (nsteps > 1)
    stage_step(gA + 32, gB + 32, lda, ldb, &lAs[1][lwoff], &lBs[1][lwoff]);

  int buf = 0;
  for (int k = 0; k < nsteps; k++) {
    // my 4 loads for tile k done; tile k+1's 4 may remain in flight
    if (k + 1 < nsteps)
      asm volatile("s_waitcnt vmcnt(4)" ::: "memory");
    else
      asm volatile("s_waitcnt vmcnt(0)" ::: "memory");
    asm volatile("s_barrier" ::: "memory");   // all waves' tile-k loads landed

    if (k + 2 < nsteps) {
      int nb = buf + 2; if (nb >= NBUF) nb -= NBUF;
      stage_step(gA + (long)(k + 2) * 32, gB + (long)(k + 2) * 32, lda, ldb,
                 &lAs[nb][lwoff], &lBs[nb][lwoff]);
    }

    const uint16_t* la = lAs[buf];
    const uint16_t* lb = lBs[buf];
    short8 af[4], bfr[4];
    #pragma unroll
    for (int mt = 0; mt < 4; mt++)
      af[mt] = *(const short8*)&la[(wr + mt * 16 + lane16) * 32 + quad * 8];
    #pragma unroll
    for (int nt = 0; nt < 4; nt++)
      bfr[nt] = *(const short8*)&lb[(wc + nt * 16 + lane16) * 32 + quad * 8];

    #pragma unroll
    for (int mt = 0; mt < 4; mt++)
      #pragma unroll
      for (int nt = 0; nt < 4; nt++)
        acc[mt][nt] = __builtin_amdgcn_mfma_f32_16x16x32_bf16(
            af[mt], bfr[nt], acc[mt][nt], 0, 0, 0);

    buf += 1; if (buf >= NBUF) buf -= NBUF;
  }
}

// epilogue index helpers: row = wr + mt*16 + quad*4 + r ; col = wc + nt*16 + lane16
#define EPI_PREAMBLE                                   \
  int lane = threadIdx.x & 63;                         \
  int wave = threadIdx.x >> 6;                         \
  int lane16 = lane & 15;                              \
  int quad = lane >> 4;                                \
  int wr = (wave >> 1) * 64;                           \
  int wc = (wave & 1) * 64;

// ---- prep kernels ----------------------------------------------------------

__global__ __launch_bounds__(256) void k_convert_x(
    const float* __restrict__ in, uint16_t* __restrict__ out, int n4)
{
  int i = blockIdx.x * blockDim.x + threadIdx.x;
  if (i >= n4) return;
  float4 v = ((const float4*)in)[i];
  ushort4 o;
  o.x = f32_to_bf16(v.x); o.y = f32_to_bf16(v.y);
  o.z = f32_to_bf16(v.z); o.w = f32_to_bf16(v.w);
  ((ushort4*)out)[i] = o;
}

// in: fp32 [R][C] -> out: bf16 [C][R]  (R,C mult of 32), block (32,8)
__global__ __launch_bounds__(256) void k_transpose_f32_bf16(
    const float* __restrict__ in, uint16_t* __restrict__ out, int R, int C)
{
  __shared__ float tile[32][33];
  int c0 = blockIdx.x * 32, r0 = blockIdx.y * 32;
  int tx = threadIdx.x, ty = threadIdx.y;
  #pragma unroll
  for (int k = 0; k < 32; k += 8)
    tile[ty + k][tx] = in[(long)(r0 + ty + k) * C + c0 + tx];
  __syncthreads();
  #pragma unroll
  for (int k = 0; k < 32; k += 8)
    out[(long)(c0 + ty + k) * R + r0 + tx] = f32_to_bf16(tile[tx][ty + k]);
}

// v bf16 [B*S][DV] -> vT bf16 [B][DV][S], block (32,8), grid (DV/32, S/32, B)
__global__ __launch_bounds__(256) void k_transpose_v(
    const uint16_t* __restrict__ v, uint16_t* __restrict__ vT)
{
  __shared__ uint16_t tile[32][33];
  int b = blockIdx.z;
  int n0 = blockIdx.x * 32, j0 = blockIdx.y * 32;
  int tx = threadIdx.x, ty = threadIdx.y;
  #pragma unroll
  for (int k = 0; k < 32; k += 8)
    tile[ty + k][tx] = v[((long)b * S_ + j0 + ty + k) * DV + n0 + tx];
  __syncthreads();
  #pragma unroll
  for (int k = 0; k < 32; k += 8)
    vT[((long)b * DV + n0 + ty + k) * S_ + j0 + tx] = tile[tx][ty + k];
}

// bias_n[n] = rel_bias[bucket(n)] * sqrt(DQK), n = i - j in [0, S)
__global__ __launch_bounds__(256) void k_bias(
    const float* __restrict__ rel, float* __restrict__ bias_n)
{
  int n = blockIdx.x * blockDim.x + threadIdx.x;
  if (n >= S_) return;
  int bucket;
  if (n < 16) {
    bucket = n;
  } else {
    float tt = logf((float)n * 0.0625f) / 2.0794415416798357f * 16.0f;
    int vl = 16 + (int)tt;
    bucket = vl < 31 ? vl : 31;
  }
  bias_n[n] = rel[bucket] * 11.313708498984761f;   // * sqrt(128)
}

// ---- GEMM kernels ----------------------------------------------------------

// fused projections: n0==0 tile -> q/k epilogue; n0>=128 -> v epilogue.
// wT: [NQV][DIM] bf16 (rows 0..127 = wqk^T, 128..1151 = wv^T)
__global__ __launch_bounds__(256) void k_gemm_qkv(
    const uint16_t* __restrict__ xb, const uint16_t* __restrict__ wT,
    const float* __restrict__ bqk, const float* __restrict__ gamma,
    const float* __restrict__ beta, const float* __restrict__ bv,
    uint16_t* __restrict__ qb, uint16_t* __restrict__ kb,
    uint16_t* __restrict__ vb)
{
  long i0 = (long)blockIdx.y * 128;
  long n0 = (long)blockIdx.x * 128;
  f32x4 acc[4][4];
  gemm128_core(xb, DIM_, wT, DIM_, i0, n0, DIM_, acc);
  EPI_PREAMBLE
  if (n0 == 0) {
    #pragma unroll
    for (int mt = 0; mt < 4; mt++)
      #pragma unroll
      for (int nt = 0; nt < 4; nt++)
        #pragma unroll
        for (int r = 0; r < 4; r++) {
          int row = wr + mt * 16 + quad * 4 + r;
          int col = wc + nt * 16 + lane16;           // 0..127 = DQK
          float vsum = acc[mt][nt][r] + bqk[col];
          float s = silu_f(vsum);
          float qv = s * gamma[col] + beta[col];
          float kv = s * gamma[DQK + col] + beta[DQK + col];
          qb[(i0 + row) * DQK + col] = f32_to_bf16(qv);
          kb[(i0 + row) * DQK + col] = f32_to_bf16(kv);
        }
  } else {
    long v0 = n0 - DQK;
    #pragma unroll
    for (int mt = 0; mt < 4; mt++)
      #pragma unroll
      for (int nt = 0; nt < 4; nt++)
        #pragma unroll
        for (int r = 0; r < 4; r++) {
          int row = wr + mt * 16 + quad * 4 + r;
          long gc = v0 + wc + nt * 16 + lane16;
          float vsum = acc[mt][nt][r] + bv[gc];
          vb[(i0 + row) * DV + gc] = f32_to_bf16(silu_f(vsum));
        }
  }
}

// attn = laplacian(q@k^T / S + bias[i-j]) masked causal, bf16 [B][S][S]
// grid (S/128 jt, S/128 it, B); upper-triangle blocks skipped (never read)
__global__ __launch_bounds__(256) void k_gemm_sim(
    const uint16_t* __restrict__ qb, const uint16_t* __restrict__ kb,
    const float* __restrict__ bias_n, uint16_t* __restrict__ attn)
{
  int bt = blockIdx.z;
  int it = blockIdx.y, jt = blockIdx.x;
  if (jt > it) return;
  long i0 = (long)it * 128, j0 = (long)jt * 128;
  const uint16_t* q = qb + (long)bt * S_ * DQK;
  const uint16_t* k = kb + (long)bt * S_ * DQK;
  f32x4 acc[4][4];
  gemm128_core(q, DQK, k, DQK, i0, j0, DQK, acc);
  uint16_t* ab = attn + (long)bt * S_ * S_;
  EPI_PREAMBLE
  #pragma unroll
  for (int mt = 0; mt < 4; mt++)
    #pragma unroll
    for (int nt = 0; nt < 4; nt++)
      #pragma unroll
      for (int r = 0; r < 4; r++) {
        long i = i0 + wr + mt * 16 + quad * 4 + r;
        long j = j0 + wc + nt * 16 + lane16;
        float aval = 0.0f;
        if (j <= i) {
          float sim = acc[mt][nt][r] * (1.0f / 2048.0f) + bias_n[i - j];
          aval = laplacian_attn(sim);
        }
        ab[i * S_ + j] = f32_to_bf16(aval);
      }
}

// out = attn @ v (fp32 out), K causally bounded at i0+128.
// grid (DV/128, 64): y encodes (b,t); it chosen so the co-resident pair
// (block c, block c+256) gets K sums ~const: it = (b&2) ? 15-t : t.
__global__ __launch_bounds__(256) void k_gemm_out(
    const uint16_t* __restrict__ attn, const uint16_t* __restrict__ vT,
    float* __restrict__ out)
{
  int y  = blockIdx.y;
  int bt = y >> 4;
  int tt = y & 15;
  int it = (bt & 2) ? (15 - tt) : tt;
  long i0 = (long)it * 128;
  long n0 = (long)blockIdx.x * 128;
  int K = (int)i0 + 128;                           // j <= i  => k < i0+128
  f32x4 acc[4][4];
  gemm128_core(attn + (long)bt * S_ * S_, S_,
               vT + (long)bt * DV * S_, S_, i0, n0, K, acc);
  EPI_PREAMBLE
  #pragma unroll
  for (int mt = 0; mt < 4; mt++)
    #pragma unroll
    for (int nt = 0; nt < 4; nt++)
      #pragma unroll
      for (int r = 0; r < 4; r++) {
        int row = wr + mt * 16 + quad * 4 + r;
        int col = wc + nt * 16 + lane16;
        out[((long)bt * S_ + i0 + row) * DV + n0 + col] = acc[mt][nt][r];
      }
}

// ---------------------------------------------------------------------------

extern "C" void kernel_launch(void* const* d_in, const int* in_sizes, int n_in,
                              void* d_out, int out_size, void* d_ws, size_t ws_size,
                              hipStream_t stream)
{
  const float* x     = (const float*)d_in[0];
  const float* wqk   = (const float*)d_in[1];
  const float* bqk   = (const float*)d_in[2];
  const float* gamma = (const float*)d_in[3];
  const float* beta  = (const float*)d_in[4];
  const float* wv    = (const float*)d_in[5];
  const float* bv    = (const float*)d_in[6];
  const float* rel   = (const float*)d_in[7];
  float* out = (float*)d_out;

  char* ws = (char*)d_ws;
  size_t off = 0;
  uint16_t* xb     = (uint16_t*)(ws + off); off += (size_t)B_ * S_ * DIM_ * 2;  // 16 MB
  uint16_t* wT     = (uint16_t*)(ws + off); off += (size_t)NQV * DIM_ * 2;      // 2.25 MB
  uint16_t* qb     = (uint16_t*)(ws + off); off += (size_t)B_ * S_ * DQK * 2;   // 2 MB
  uint16_t* kb     = (uint16_t*)(ws + off); off += (size_t)B_ * S_ * DQK * 2;   // 2 MB
  uint16_t* vb     = (uint16_t*)(ws + off); off += (size_t)B_ * S_ * DV * 2;    // 16 MB
  uint16_t* vT     = (uint16_t*)(ws + off); off += (size_t)B_ * DV * S_ * 2;    // 16 MB
  uint16_t* attn   = (uint16_t*)(ws + off); off += (size_t)B_ * S_ * S_ * 2;    // 32 MB
  float*    bias_n = (float*)(ws + off);    off += (size_t)S_ * 4;              // 8 KB

  const int n_x = B_ * S_ * DIM_;
  k_convert_x<<<dim3((n_x / 4 + 255) / 256), dim3(256), 0, stream>>>(x, xb, n_x / 4);
  k_transpose_f32_bf16<<<dim3(DQK / 32, DIM_ / 32), dim3(32, 8), 0, stream>>>(wqk, wT, DIM_, DQK);
  k_transpose_f32_bf16<<<dim3(DV / 32, DIM_ / 32), dim3(32, 8), 0, stream>>>(wv, wT + (size_t)DQK * DIM_, DIM_, DV);
  k_bias<<<dim3(S_ / 256), dim3(256), 0, stream>>>(rel, bias_n);

  k_gemm_qkv<<<dim3(NQV / 128, B_ * S_ / 128), dim3(256), 0, stream>>>(
      xb, wT, bqk, gamma, beta, bv, qb, kb, vb);
  k_transpose_v<<<dim3(DV / 32, S_ / 32, B_), dim3(32, 8), 0, stream>>>(vb, vT);
  k_gemm_sim<<<dim3(S_ / 128, S_ / 128, B_), dim3(256), 0, stream>>>(qb, kb, bias_n, attn);
  k_gemm_out<<<dim3(DV / 128, 64), dim3(256), 0, stream>>>(attn, vT, out);
}

// Round 4
// 255.624 us; speedup vs baseline: 1.0744x; 1.0049x over previous
//
#include <hip/hip_runtime.h>
#include <stdint.h>

// ---------------------------------------------------------------------------
// SingleHeadedAttention (Mega-style, laplacian attn fn, causal, T5 rel bias)
// B=4, S=2048, DIM=1024, DQK=128, DV=1024.  fp32 in/out, bf16 MFMA internals.
// R3: depth-4 software pipeline, 5-buffer LDS ring (80 KB -> 2 blocks/CU).
//     Main loop: s_waitcnt vmcnt(12) (3 tiles stay in flight) + raw s_barrier;
//     drain phase tapers vmcnt 8/4/0 -> core is correct for any nsteps >= 4.
// ---------------------------------------------------------------------------

#define B_   4
#define S_   2048
#define DIM_ 1024
#define DQK  128
#define DV   1024
#define NQV  (DQK + DV)   // 1152

#define NBUF 5            // LDS ring buffers (pipeline depth 4)

typedef __attribute__((ext_vector_type(8))) short short8;   // 8 bf16 (4 VGPRs)
typedef __attribute__((ext_vector_type(4))) float f32x4;    // MFMA C/D

__device__ __forceinline__ uint16_t f32_to_bf16(float f) {
  uint32_t u = __float_as_uint(f);
  u += 0x7FFFu + ((u >> 16) & 1u);          // round-to-nearest-even
  return (uint16_t)(u >> 16);
}

__device__ __forceinline__ float silu_f(float x) {
  return x / (1.0f + expf(-x));
}

__device__ __forceinline__ float laplacian_attn(float x) {
  // (1 + erf((x - sqrt(0.5)) / sqrt(0.5*pi))) * 0.5
  return 0.5f * (1.0f + erff((x - 0.70710678118654752f) * 0.79788456080286536f));
}

// async 16B global->LDS (lands at lds_base + lane*16)
__device__ __forceinline__ void async_ld16(const void* g, void* l) {
  __builtin_amdgcn_global_load_lds(
      (const __attribute__((address_space(1))) void*)g,
      (__attribute__((address_space(3))) void*)l, 16, 0, 0);
}

// stage one 32-wide k-slab for this wave: 4 vmcnt-counted instructions
// (A rows srow, srow+16; B rows srow, srow+16), 16B per lane each.
__device__ __forceinline__ void stage_step(
    const uint16_t* gA, const uint16_t* gB, long lda, long ldb,
    uint16_t* lA, uint16_t* lB)
{
  async_ld16(gA,            lA);
  async_ld16(gA + 16 * lda, lA + 16 * 32);
  async_ld16(gB,            lB);
  async_ld16(gB + 16 * ldb, lB + 16 * 32);
}

// ---- core: 128x128 output tile, C = A(rows i0..) * Bt(rows n0..)^T --------
// A: [M][lda] bf16 row-major, Bt: [N][ldb] bf16 row-major (i.e. B^T), k-contig.
// K multiple of 32, K >= 128; rows 16B-aligned. Unpadded LDS tiles 128x32.
// Pipeline depth 4, ring of 5: at step k, tiles k+1..k+3 stay in flight
// (vmcnt(12)); step k issues tile k+4 into buf (k+4)%5 (!= buf k%5).
// Drain (last 3 steps) tapers vmcnt 8/4/0 -> correct for any nsteps >= 4.
// Overwrite safety: all waves' step-(k-1) ds_reads retire before their
// barrier(k) (lgkm waits precede the MFMAs), DMA issue follows barrier(k).
__device__ __forceinline__ void gemm128_core(
    const uint16_t* __restrict__ A, int lda,
    const uint16_t* __restrict__ Bt, int ldb,
    long i0, long n0, int K, f32x4 acc[4][4])
{
  __shared__ uint16_t lAs[NBUF][128 * 32];
  __shared__ uint16_t lBs[NBUF][128 * 32];

  const int t      = threadIdx.x;          // 0..255
  const int lane   = t & 63;
  const int wave   = t >> 6;
  const int lane16 = lane & 15;
  const int quad   = lane >> 4;
  const int wr     = (wave >> 1) * 64;     // wave row offset in 128-tile
  const int wc     = (wave & 1) * 64;      // wave col offset

  #pragma unroll
  for (int mt = 0; mt < 4; mt++)
    #pragma unroll
    for (int nt = 0; nt < 4; nt++) {
      f32x4 z = {0.0f, 0.0f, 0.0f, 0.0f};
      acc[mt][nt] = z;
    }

  // staging geometry: wave w covers rows w*32 .. w*32+31 (two 16-row insns),
  // lane l -> row base+(l>>2), k-elems (l&3)*8 .. +7; LDS dst base + l*16.
  const int srow = wave * 32 + (lane >> 2);
  const int scol = (lane & 3) * 8;
  const uint16_t* gA = A  + (i0 + srow) * (long)lda + scol;
  const uint16_t* gB = Bt + (n0 + srow) * (long)ldb + scol;
  const int lwoff = wave * 32 * 32;        // wave's element offset in a buffer

  const int nsteps = K >> 5;               // >= 4 guaranteed by callers

  auto compute_step = [&](int bidx) {
    const uint16_t* la = lAs[bidx];
    const uint16_t* lb = lBs[bidx];
    short8 af[4], bfr[4];
    #pragma unroll
    for (int mt = 0; mt < 4; mt++)
      af[mt] = *(const short8*)&la[(wr + mt * 16 + lane16) * 32 + quad * 8];
    #pragma unroll
    for (int nt = 0; nt < 4; nt++)
      bfr[nt] = *(const short8*)&lb[(wc + nt * 16 + lane16) * 32 + quad * 8];
    #pragma unroll
    for (int mt = 0; mt < 4; mt++)
      #pragma unroll
      for (int nt = 0; nt < 4; nt++)
        acc[mt][nt] = __builtin_amdgcn_mfma_f32_16x16x32_bf16(
            af[mt], bfr[nt], acc[mt][nt], 0, 0, 0);
  };

  // prologue: stage tiles 0..3 into bufs 0..3
  #pragma unroll
  for (int p = 0; p < 4; p++)
    stage_step(gA + p * 32, gB + p * 32, lda, ldb,
               &lAs[p][lwoff], &lBs[p][lwoff]);

  int buf = 0;           // k % NBUF
  int nbuf = 4;          // (k+4) % NBUF
  // main: k = 0 .. nsteps-4  (tiles k+1..k+3 remain in flight)
  for (int k = 0; k <= nsteps - 4; k++) {
    asm volatile("s_waitcnt vmcnt(12)" ::: "memory");
    asm volatile("s_barrier" ::: "memory");
    if (k + 4 < nsteps)
      stage_step(gA + (long)(k + 4) * 32, gB + (long)(k + 4) * 32, lda, ldb,
                 &lAs[nbuf][lwoff], &lBs[nbuf][lwoff]);
    compute_step(buf);
    buf++;  if (buf  == NBUF) buf  = 0;
    nbuf++; if (nbuf == NBUF) nbuf = 0;
  }
  // drain: last 3 steps, decreasing in-flight allowance
  asm volatile("s_waitcnt vmcnt(8)" ::: "memory");
  asm volatile("s_barrier" ::: "memory");
  compute_step(buf);
  buf++; if (buf == NBUF) buf = 0;
  asm volatile("s_waitcnt vmcnt(4)" ::: "memory");
  asm volatile("s_barrier" ::: "memory");
  compute_step(buf);
  buf++; if (buf == NBUF) buf = 0;
  asm volatile("s_waitcnt vmcnt(0)" ::: "memory");
  asm volatile("s_barrier" ::: "memory");
  compute_step(buf);
}

// epilogue index helpers: row = wr + mt*16 + quad*4 + r ; col = wc + nt*16 + lane16
#define EPI_PREAMBLE                                   \
  int lane = threadIdx.x & 63;                         \
  int wave = threadIdx.x >> 6;                         \
  int lane16 = lane & 15;                              \
  int quad = lane >> 4;                                \
  int wr = (wave >> 1) * 64;                           \
  int wc = (wave & 1) * 64;

// ---- prep kernels ----------------------------------------------------------

__global__ __launch_bounds__(256) void k_convert_x(
    const float* __restrict__ in, uint16_t* __restrict__ out, int n4)
{
  int i = blockIdx.x * blockDim.x + threadIdx.x;
  if (i >= n4) return;
  float4 v = ((const float4*)in)[i];
  ushort4 o;
  o.x = f32_to_bf16(v.x); o.y = f32_to_bf16(v.y);
  o.z = f32_to_bf16(v.z); o.w = f32_to_bf16(v.w);
  ((ushort4*)out)[i] = o;
}

// in: fp32 [R][C] -> out: bf16 [C][R]  (R,C mult of 32), block (32,8)
__global__ __launch_bounds__(256) void k_transpose_f32_bf16(
    const float* __restrict__ in, uint16_t* __restrict__ out, int R, int C)
{
  __shared__ float tile[32][33];
  int c0 = blockIdx.x * 32, r0 = blockIdx.y * 32;
  int tx = threadIdx.x, ty = threadIdx.y;
  #pragma unroll
  for (int k = 0; k < 32; k += 8)
    tile[ty + k][tx] = in[(long)(r0 + ty + k) * C + c0 + tx];
  __syncthreads();
  #pragma unroll
  for (int k = 0; k < 32; k += 8)
    out[(long)(c0 + ty + k) * R + r0 + tx] = f32_to_bf16(tile[tx][ty + k]);
}

// v bf16 [B*S][DV] -> vT bf16 [B][DV][S], block (32,8), grid (DV/32, S/32, B)
__global__ __launch_bounds__(256) void k_transpose_v(
    const uint16_t* __restrict__ v, uint16_t* __restrict__ vT)
{
  __shared__ uint16_t tile[32][33];
  int b = blockIdx.z;
  int n0 = blockIdx.x * 32, j0 = blockIdx.y * 32;
  int tx = threadIdx.x, ty = threadIdx.y;
  #pragma unroll
  for (int k = 0; k < 32; k += 8)
    tile[ty + k][tx] = v[((long)b * S_ + j0 + ty + k) * DV + n0 + tx];
  __syncthreads();
  #pragma unroll
  for (int k = 0; k < 32; k += 8)
    vT[((long)b * DV + n0 + ty + k) * S_ + j0 + tx] = tile[tx][ty + k];
}

// bias_n[n] = rel_bias[bucket(n)] * sqrt(DQK), n = i - j in [0, S)
__global__ __launch_bounds__(256) void k_bias(
    const float* __restrict__ rel, float* __restrict__ bias_n)
{
  int n = blockIdx.x * blockDim.x + threadIdx.x;
  if (n >= S_) return;
  int bucket;
  if (n < 16) {
    bucket = n;
  } else {
    float tt = logf((float)n * 0.0625f) / 2.0794415416798357f * 16.0f;
    int vl = 16 + (int)tt;
    bucket = vl < 31 ? vl : 31;
  }
  bias_n[n] = rel[bucket] * 11.313708498984761f;   // * sqrt(128)
}

// ---- GEMM kernels ----------------------------------------------------------

// fused projections: n0==0 tile -> q/k epilogue; n0>=128 -> v epilogue.
// wT: [NQV][DIM] bf16 (rows 0..127 = wqk^T, 128..1151 = wv^T)
__global__ __launch_bounds__(256, 2) void k_gemm_qkv(
    const uint16_t* __restrict__ xb, const uint16_t* __restrict__ wT,
    const float* __restrict__ bqk, const float* __restrict__ gamma,
    const float* __restrict__ beta, const float* __restrict__ bv,
    uint16_t* __restrict__ qb, uint16_t* __restrict__ kb,
    uint16_t* __restrict__ vb)
{
  long i0 = (long)blockIdx.y * 128;
  long n0 = (long)blockIdx.x * 128;
  f32x4 acc[4][4];
  gemm128_core(xb, DIM_, wT, DIM_, i0, n0, DIM_, acc);
  EPI_PREAMBLE
  if (n0 == 0) {
    #pragma unroll
    for (int mt = 0; mt < 4; mt++)
      #pragma unroll
      for (int nt = 0; nt < 4; nt++)
        #pragma unroll
        for (int r = 0; r < 4; r++) {
          int row = wr + mt * 16 + quad * 4 + r;
          int col = wc + nt * 16 + lane16;           // 0..127 = DQK
          float vsum = acc[mt][nt][r] + bqk[col];
          float s = silu_f(vsum);
          float qv = s * gamma[col] + beta[col];
          float kv = s * gamma[DQK + col] + beta[DQK + col];
          qb[(i0 + row) * DQK + col] = f32_to_bf16(qv);
          kb[(i0 + row) * DQK + col] = f32_to_bf16(kv);
        }
  } else {
    long v0 = n0 - DQK;
    #pragma unroll
    for (int mt = 0; mt < 4; mt++)
      #pragma unroll
      for (int nt = 0; nt < 4; nt++)
        #pragma unroll
        for (int r = 0; r < 4; r++) {
          int row = wr + mt * 16 + quad * 4 + r;
          long gc = v0 + wc + nt * 16 + lane16;
          float vsum = acc[mt][nt][r] + bv[gc];
          vb[(i0 + row) * DV + gc] = f32_to_bf16(silu_f(vsum));
        }
  }
}

// attn = laplacian(q@k^T / S + bias[i-j]) masked causal, bf16 [B][S][S]
// grid (S/128 jt, S/128 it, B); upper-triangle blocks skipped (never read)
__global__ __launch_bounds__(256, 2) void k_gemm_sim(
    const uint16_t* __restrict__ qb, const uint16_t* __restrict__ kb,
    const float* __restrict__ bias_n, uint16_t* __restrict__ attn)
{
  int bt = blockIdx.z;
  int it = blockIdx.y, jt = blockIdx.x;
  if (jt > it) return;
  long i0 = (long)it * 128, j0 = (long)jt * 128;
  const uint16_t* q = qb + (long)bt * S_ * DQK;
  const uint16_t* k = kb + (long)bt * S_ * DQK;
  f32x4 acc[4][4];
  gemm128_core(q, DQK, k, DQK, i0, j0, DQK, acc);
  uint16_t* ab = attn + (long)bt * S_ * S_;
  EPI_PREAMBLE
  #pragma unroll
  for (int mt = 0; mt < 4; mt++)
    #pragma unroll
    for (int nt = 0; nt < 4; nt++)
      #pragma unroll
      for (int r = 0; r < 4; r++) {
        long i = i0 + wr + mt * 16 + quad * 4 + r;
        long j = j0 + wc + nt * 16 + lane16;
        float aval = 0.0f;
        if (j <= i) {
          float sim = acc[mt][nt][r] * (1.0f / 2048.0f) + bias_n[i - j];
          aval = laplacian_attn(sim);
        }
        ab[i * S_ + j] = f32_to_bf16(aval);
      }
}

// out = attn @ v (fp32 out), K causally bounded at i0+128.
// grid (DV/128, 64): y encodes (b,t); it chosen so the co-resident pair
// (block c, block c+256) gets K sums ~const: it = (b&2) ? 15-t : t.
__global__ __launch_bounds__(256, 2) void k_gemm_out(
    const uint16_t* __restrict__ attn, const uint16_t* __restrict__ vT,
    float* __restrict__ out)
{
  int y  = blockIdx.y;
  int bt = y >> 4;
  int tt = y & 15;
  int it = (bt & 2) ? (15 - tt) : tt;
  long i0 = (long)it * 128;
  long n0 = (long)blockIdx.x * 128;
  int K = (int)i0 + 128;                           // j <= i  => k < i0+128
  f32x4 acc[4][4];
  gemm128_core(attn + (long)bt * S_ * S_, S_,
               vT + (long)bt * DV * S_, S_, i0, n0, K, acc);
  EPI_PREAMBLE
  #pragma unroll
  for (int mt = 0; mt < 4; mt++)
    #pragma unroll
    for (int nt = 0; nt < 4; nt++)
      #pragma unroll
      for (int r = 0; r < 4; r++) {
        int row = wr + mt * 16 + quad * 4 + r;
        int col = wc + nt * 16 + lane16;
        out[((long)bt * S_ + i0 + row) * DV + n0 + col] = acc[mt][nt][r];
      }
}

// ---------------------------------------------------------------------------

extern "C" void kernel_launch(void* const* d_in, const int* in_sizes, int n_in,
                              void* d_out, int out_size, void* d_ws, size_t ws_size,
                              hipStream_t stream)
{
  const float* x     = (const float*)d_in[0];
  const float* wqk   = (const float*)d_in[1];
  const float* bqk   = (const float*)d_in[2];
  const float* gamma = (const float*)d_in[3];
  const float* beta  = (const float*)d_in[4];
  const float* wv    = (const float*)d_in[5];
  const float* bv    = (const float*)d_in[6];
  const float* rel   = (const float*)d_in[7];
  float* out = (float*)d_out;

  char* ws = (char*)d_ws;
  size_t off = 0;
  uint16_t* xb     = (uint16_t*)(ws + off); off += (size_t)B_ * S_ * DIM_ * 2;  // 16 MB
  uint16_t* wT     = (uint16_t*)(ws + off); off += (size_t)NQV * DIM_ * 2;      // 2.25 MB
  uint16_t* qb     = (uint16_t*)(ws + off); off += (size_t)B_ * S_ * DQK * 2;   // 2 MB
  uint16_t* kb     = (uint16_t*)(ws + off); off += (size_t)B_ * S_ * DQK * 2;   // 2 MB
  uint16_t* vb     = (uint16_t*)(ws + off); off += (size_t)B_ * S_ * DV * 2;    // 16 MB
  uint16_t* vT     = (uint16_t*)(ws + off); off += (size_t)B_ * DV * S_ * 2;    // 16 MB
  uint16_t* attn   = (uint16_t*)(ws + off); off += (size_t)B_ * S_ * S_ * 2;    // 32 MB
  float*    bias_n = (float*)(ws + off);    off += (size_t)S_ * 4;              // 8 KB

  const int n_x = B_ * S_ * DIM_;
  k_convert_x<<<dim3((n_x / 4 + 255) / 256), dim3(256), 0, stream>>>(x, xb, n_x / 4);
  k_transpose_f32_bf16<<<dim3(DQK / 32, DIM_ / 32), dim3(32, 8), 0, stream>>>(wqk, wT, DIM_, DQK);
  k_transpose_f32_bf16<<<dim3(DV / 32, DIM_ / 32), dim3(32, 8), 0, stream>>>(wv, wT + (size_t)DQK * DIM_, DIM_, DV);
  k_bias<<<dim3(S_ / 256), dim3(256), 0, stream>>>(rel, bias_n);

  k_gemm_qkv<<<dim3(NQV / 128, B_ * S_ / 128), dim3(256), 0, stream>>>(
      xb, wT, bqk, gamma, beta, bv, qb, kb, vb);
  k_transpose_v<<<dim3(DV / 32, S_ / 32, B_), dim3(32, 8), 0, stream>>>(vb, vT);
  k_gemm_sim<<<dim3(S_ / 128, S_ / 128, B_), dim3(256), 0, stream>>>(qb, kb, bias_n, attn);
  k_gemm_out<<<dim3(DV / 128, 64), dim3(256), 0, stream>>>(attn, vT, out);
}

// Round 5
// 226.851 us; speedup vs baseline: 1.2106x; 1.1268x over previous
//
#include <hip/hip_runtime.h>
#include <stdint.h>

// ---------------------------------------------------------------------------
// SingleHeadedAttention (Mega-style, laplacian attn fn, causal, T5 rel bias)
// B=4, S=2048, DIM=1024, DQK=128, DV=1024.  fp32 in/out, bf16 MFMA internals.
// R4: 128x64 tiles -> 2x the blocks (>=4 blocks/CU), NBUF=3 ring (36 KB LDS),
//     __launch_bounds__(256,4) for 4 blocks/CU. R3 post-mortem: pipeline depth
//     was saturated; occupancy (inter-block overlap) is the binding constraint
//     (m102: 320 TF @ 2 blocks/CU vs 833 TF @ 4 blocks/CU, same structure).
// ---------------------------------------------------------------------------

#define B_   4
#define S_   2048
#define DIM_ 1024
#define DQK  128
#define DV   1024
#define NQV  (DQK + DV)   // 1152

#define NBUF 3            // LDS ring buffers (pipeline depth 2)

typedef __attribute__((ext_vector_type(8))) short short8;   // 8 bf16 (4 VGPRs)
typedef __attribute__((ext_vector_type(4))) float f32x4;    // MFMA C/D

__device__ __forceinline__ uint16_t f32_to_bf16(float f) {
  uint32_t u = __float_as_uint(f);
  u += 0x7FFFu + ((u >> 16) & 1u);          // round-to-nearest-even
  return (uint16_t)(u >> 16);
}

__device__ __forceinline__ float silu_f(float x) {
  return x / (1.0f + expf(-x));
}

__device__ __forceinline__ float laplacian_attn(float x) {
  // (1 + erf((x - sqrt(0.5)) / sqrt(0.5*pi))) * 0.5
  return 0.5f * (1.0f + erff((x - 0.70710678118654752f) * 0.79788456080286536f));
}

// async 16B global->LDS (lands at lds_base + lane*16)
__device__ __forceinline__ void async_ld16(const void* g, void* l) {
  __builtin_amdgcn_global_load_lds(
      (const __attribute__((address_space(1))) void*)g,
      (__attribute__((address_space(3))) void*)l, 16, 0, 0);
}

// ---- core: 128x64 output tile, C = A(rows i0..) * Bt(rows n0..)^T ---------
// A: [M][lda] bf16 row-major, Bt: [N][ldb] bf16 row-major (i.e. B^T), k-contig.
// K multiple of 32, nsteps >= 2; rows 16B-aligned.
// LDS per stage: A 128x32 (8 KB) + B 64x32 (4 KB); ring of 3 = 36 KB.
// Staging per wave per step: 3 async_ld16 (A rows w*32, w*32+16; B rows w*16).
// Wave w computes rows w*32..w*32+31, all 64 cols: acc[2][4].
// Pipeline depth 2: at step k wait vmcnt(3) (tile k landed, k+1 in flight),
// raw s_barrier, stage tile k+2 into buf (k+2)%3, compute tile k.
__device__ __forceinline__ void gemm_core64(
    const uint16_t* __restrict__ A, int lda,
    const uint16_t* __restrict__ Bt, int ldb,
    long i0, long n0, int K, f32x4 acc[2][4])
{
  __shared__ uint16_t lAs[NBUF][128 * 32];
  __shared__ uint16_t lBs[NBUF][64 * 32];

  const int t      = threadIdx.x;          // 0..255
  const int lane   = t & 63;
  const int wave   = t >> 6;
  const int lane16 = lane & 15;
  const int quad   = lane >> 4;

  #pragma unroll
  for (int mt = 0; mt < 2; mt++)
    #pragma unroll
    for (int nt = 0; nt < 4; nt++) {
      f32x4 z = {0.0f, 0.0f, 0.0f, 0.0f};
      acc[mt][nt] = z;
    }

  // staging geometry: lane l -> row (l>>2), k-elems (l&3)*8..+7; dst + l*16B.
  const int lrow = lane >> 2;
  const int scol = (lane & 3) * 8;
  const uint16_t* gA = A  + (i0 + wave * 32 + lrow) * (long)lda + scol;
  const uint16_t* gB = Bt + (n0 + wave * 16 + lrow) * (long)ldb + scol;
  const int lwa = wave * 32 * 32;          // wave's A offset in a buffer
  const int lwb = wave * 16 * 32;          // wave's B offset in a buffer

  const int nsteps = K >> 5;               // >= 2 guaranteed by callers

  auto stage = [&](int kk, int bidx) {
    const uint16_t* a = gA + (long)kk * 32;
    async_ld16(a,            &lAs[bidx][lwa]);
    async_ld16(a + 16 * lda, &lAs[bidx][lwa + 16 * 32]);
    async_ld16(gB + (long)kk * 32, &lBs[bidx][lwb]);
  };

  auto compute = [&](int bidx) {
    const uint16_t* la = lAs[bidx];
    const uint16_t* lb = lBs[bidx];
    short8 af[2], bfr[4];
    #pragma unroll
    for (int mt = 0; mt < 2; mt++)
      af[mt] = *(const short8*)&la[(wave * 32 + mt * 16 + lane16) * 32 + quad * 8];
    #pragma unroll
    for (int nt = 0; nt < 4; nt++)
      bfr[nt] = *(const short8*)&lb[(nt * 16 + lane16) * 32 + quad * 8];
    #pragma unroll
    for (int mt = 0; mt < 2; mt++)
      #pragma unroll
      for (int nt = 0; nt < 4; nt++)
        acc[mt][nt] = __builtin_amdgcn_mfma_f32_16x16x32_bf16(
            af[mt], bfr[nt], acc[mt][nt], 0, 0, 0);
  };

  // prologue: stage tiles 0,1 into bufs 0,1
  stage(0, 0);
  stage(1, 1);

  int buf = 0;           // k % NBUF
  int nbuf = 2;          // (k+2) % NBUF
  for (int k = 0; k < nsteps; k++) {
    if (k + 1 < nsteps)
      asm volatile("s_waitcnt vmcnt(3)" ::: "memory");
    else
      asm volatile("s_waitcnt vmcnt(0)" ::: "memory");
    asm volatile("s_barrier" ::: "memory");
    if (k + 2 < nsteps)
      stage(k + 2, nbuf);
    compute(buf);
    buf++;  if (buf  == NBUF) buf  = 0;
    nbuf++; if (nbuf == NBUF) nbuf = 0;
  }
}

// epilogue mapping: row = wave*32 + mt*16 + quad*4 + r ; col = nt*16 + lane16
#define EPI_PREAMBLE                                   \
  int lane = threadIdx.x & 63;                         \
  int wave = threadIdx.x >> 6;                         \
  int lane16 = lane & 15;                              \
  int quad = lane >> 4;

// ---- prep kernels ----------------------------------------------------------

__global__ __launch_bounds__(256) void k_convert_x(
    const float* __restrict__ in, uint16_t* __restrict__ out, int n4)
{
  int i = blockIdx.x * blockDim.x + threadIdx.x;
  if (i >= n4) return;
  float4 v = ((const float4*)in)[i];
  ushort4 o;
  o.x = f32_to_bf16(v.x); o.y = f32_to_bf16(v.y);
  o.z = f32_to_bf16(v.z); o.w = f32_to_bf16(v.w);
  ((ushort4*)out)[i] = o;
}

// in: fp32 [R][C] -> out: bf16 [C][R]  (R,C mult of 32), block (32,8)
__global__ __launch_bounds__(256) void k_transpose_f32_bf16(
    const float* __restrict__ in, uint16_t* __restrict__ out, int R, int C)
{
  __shared__ float tile[32][33];
  int c0 = blockIdx.x * 32, r0 = blockIdx.y * 32;
  int tx = threadIdx.x, ty = threadIdx.y;
  #pragma unroll
  for (int k = 0; k < 32; k += 8)
    tile[ty + k][tx] = in[(long)(r0 + ty + k) * C + c0 + tx];
  __syncthreads();
  #pragma unroll
  for (int k = 0; k < 32; k += 8)
    out[(long)(c0 + ty + k) * R + r0 + tx] = f32_to_bf16(tile[tx][ty + k]);
}

// v bf16 [B*S][DV] -> vT bf16 [B][DV][S], block (32,8), grid (DV/32, S/32, B)
__global__ __launch_bounds__(256) void k_transpose_v(
    const uint16_t* __restrict__ v, uint16_t* __restrict__ vT)
{
  __shared__ uint16_t tile[32][33];
  int b = blockIdx.z;
  int n0 = blockIdx.x * 32, j0 = blockIdx.y * 32;
  int tx = threadIdx.x, ty = threadIdx.y;
  #pragma unroll
  for (int k = 0; k < 32; k += 8)
    tile[ty + k][tx] = v[((long)b * S_ + j0 + ty + k) * DV + n0 + tx];
  __syncthreads();
  #pragma unroll
  for (int k = 0; k < 32; k += 8)
    vT[((long)b * DV + n0 + ty + k) * S_ + j0 + tx] = tile[tx][ty + k];
}

// bias_n[n] = rel_bias[bucket(n)] * sqrt(DQK), n = i - j in [0, S)
__global__ __launch_bounds__(256) void k_bias(
    const float* __restrict__ rel, float* __restrict__ bias_n)
{
  int n = blockIdx.x * blockDim.x + threadIdx.x;
  if (n >= S_) return;
  int bucket;
  if (n < 16) {
    bucket = n;
  } else {
    float tt = logf((float)n * 0.0625f) / 2.0794415416798357f * 16.0f;
    int vl = 16 + (int)tt;
    bucket = vl < 31 ? vl : 31;
  }
  bias_n[n] = rel[bucket] * 11.313708498984761f;   // * sqrt(128)
}

// ---- GEMM kernels ----------------------------------------------------------

// fused projections: n0 in {0,64} -> q/k epilogue; n0>=128 -> v epilogue.
// wT: [NQV][DIM] bf16 (rows 0..127 = wqk^T, 128..1151 = wv^T)
__global__ __launch_bounds__(256, 4) void k_gemm_qkv(
    const uint16_t* __restrict__ xb, const uint16_t* __restrict__ wT,
    const float* __restrict__ bqk, const float* __restrict__ gamma,
    const float* __restrict__ beta, const float* __restrict__ bv,
    uint16_t* __restrict__ qb, uint16_t* __restrict__ kb,
    uint16_t* __restrict__ vb)
{
  long i0 = (long)blockIdx.y * 128;
  long n0 = (long)blockIdx.x * 64;
  f32x4 acc[2][4];
  gemm_core64(xb, DIM_, wT, DIM_, i0, n0, DIM_, acc);
  EPI_PREAMBLE
  if (n0 < DQK) {
    #pragma unroll
    for (int mt = 0; mt < 2; mt++)
      #pragma unroll
      for (int nt = 0; nt < 4; nt++)
        #pragma unroll
        for (int r = 0; r < 4; r++) {
          int row = wave * 32 + mt * 16 + quad * 4 + r;
          int col = (int)n0 + nt * 16 + lane16;      // 0..127 = DQK
          float vsum = acc[mt][nt][r] + bqk[col];
          float s = silu_f(vsum);
          float qv = s * gamma[col] + beta[col];
          float kv = s * gamma[DQK + col] + beta[DQK + col];
          qb[(i0 + row) * DQK + col] = f32_to_bf16(qv);
          kb[(i0 + row) * DQK + col] = f32_to_bf16(kv);
        }
  } else {
    long v0 = n0 - DQK;
    #pragma unroll
    for (int mt = 0; mt < 2; mt++)
      #pragma unroll
      for (int nt = 0; nt < 4; nt++)
        #pragma unroll
        for (int r = 0; r < 4; r++) {
          int row = wave * 32 + mt * 16 + quad * 4 + r;
          long gc = v0 + nt * 16 + lane16;
          float vsum = acc[mt][nt][r] + bv[gc];
          vb[(i0 + row) * DV + gc] = f32_to_bf16(silu_f(vsum));
        }
  }
}

// attn = laplacian(q@k^T / S + bias[i-j]) masked causal, bf16 [B][S][S]
// grid (S/64 jt, S/128 it, B); strictly-upper tiles skipped (never read)
__global__ __launch_bounds__(256, 4) void k_gemm_sim(
    const uint16_t* __restrict__ qb, const uint16_t* __restrict__ kb,
    const float* __restrict__ bias_n, uint16_t* __restrict__ attn)
{
  int bt = blockIdx.z;
  int it = blockIdx.y, jt = blockIdx.x;
  long i0 = (long)it * 128, j0 = (long)jt * 64;
  if (j0 > i0 + 127) return;
  const uint16_t* q = qb + (long)bt * S_ * DQK;
  const uint16_t* k = kb + (long)bt * S_ * DQK;
  f32x4 acc[2][4];
  gemm_core64(q, DQK, k, DQK, i0, j0, DQK, acc);
  uint16_t* ab = attn + (long)bt * S_ * S_;
  EPI_PREAMBLE
  #pragma unroll
  for (int mt = 0; mt < 2; mt++)
    #pragma unroll
    for (int nt = 0; nt < 4; nt++)
      #pragma unroll
      for (int r = 0; r < 4; r++) {
        long i = i0 + wave * 32 + mt * 16 + quad * 4 + r;
        long j = j0 + nt * 16 + lane16;
        float aval = 0.0f;
        if (j <= i) {
          float sim = acc[mt][nt][r] * (1.0f / 2048.0f) + bias_n[i - j];
          aval = laplacian_attn(sim);
        }
        ab[i * S_ + j] = f32_to_bf16(aval);
      }
}

// out = attn @ v (fp32 out), K causally bounded at i0+128.
// grid (DV/64, 64): y = bt*16 + tt; it = (bt&1) ? 15-tt : tt so co-resident
// block groups (c, c+256, ...) get ~constant K sums.
__global__ __launch_bounds__(256, 4) void k_gemm_out(
    const uint16_t* __restrict__ attn, const uint16_t* __restrict__ vT,
    float* __restrict__ out)
{
  int y  = blockIdx.y;
  int bt = y >> 4;
  int tt = y & 15;
  int it = (bt & 1) ? (15 - tt) : tt;
  long i0 = (long)it * 128;
  long n0 = (long)blockIdx.x * 64;
  int K = (int)i0 + 128;                           // j <= i  => k < i0+128
  f32x4 acc[2][4];
  gemm_core64(attn + (long)bt * S_ * S_, S_,
              vT + (long)bt * DV * S_, S_, i0, n0, K, acc);
  EPI_PREAMBLE
  #pragma unroll
  for (int mt = 0; mt < 2; mt++)
    #pragma unroll
    for (int nt = 0; nt < 4; nt++)
      #pragma unroll
      for (int r = 0; r < 4; r++) {
        int row = wave * 32 + mt * 16 + quad * 4 + r;
        int col = nt * 16 + lane16;
        out[((long)bt * S_ + i0 + row) * DV + n0 + col] = acc[mt][nt][r];
      }
}

// ---------------------------------------------------------------------------

extern "C" void kernel_launch(void* const* d_in, const int* in_sizes, int n_in,
                              void* d_out, int out_size, void* d_ws, size_t ws_size,
                              hipStream_t stream)
{
  const float* x     = (const float*)d_in[0];
  const float* wqk   = (const float*)d_in[1];
  const float* bqk   = (const float*)d_in[2];
  const float* gamma = (const float*)d_in[3];
  const float* beta  = (const float*)d_in[4];
  const float* wv    = (const float*)d_in[5];
  const float* bv    = (const float*)d_in[6];
  const float* rel   = (const float*)d_in[7];
  float* out = (float*)d_out;

  char* ws = (char*)d_ws;
  size_t off = 0;
  uint16_t* xb     = (uint16_t*)(ws + off); off += (size_t)B_ * S_ * DIM_ * 2;  // 16 MB
  uint16_t* wT     = (uint16_t*)(ws + off); off += (size_t)NQV * DIM_ * 2;      // 2.25 MB
  uint16_t* qb     = (uint16_t*)(ws + off); off += (size_t)B_ * S_ * DQK * 2;   // 2 MB
  uint16_t* kb     = (uint16_t*)(ws + off); off += (size_t)B_ * S_ * DQK * 2;   // 2 MB
  uint16_t* vb     = (uint16_t*)(ws + off); off += (size_t)B_ * S_ * DV * 2;    // 16 MB
  uint16_t* vT     = (uint16_t*)(ws + off); off += (size_t)B_ * DV * S_ * 2;    // 16 MB
  uint16_t* attn   = (uint16_t*)(ws + off); off += (size_t)B_ * S_ * S_ * 2;    // 32 MB
  float*    bias_n = (float*)(ws + off);    off += (size_t)S_ * 4;              // 8 KB

  const int n_x = B_ * S_ * DIM_;
  k_convert_x<<<dim3((n_x / 4 + 255) / 256), dim3(256), 0, stream>>>(x, xb, n_x / 4);
  k_transpose_f32_bf16<<<dim3(DQK / 32, DIM_ / 32), dim3(32, 8), 0, stream>>>(wqk, wT, DIM_, DQK);
  k_transpose_f32_bf16<<<dim3(DV / 32, DIM_ / 32), dim3(32, 8), 0, stream>>>(wv, wT + (size_t)DQK * DIM_, DIM_, DV);
  k_bias<<<dim3(S_ / 256), dim3(256), 0, stream>>>(rel, bias_n);

  k_gemm_qkv<<<dim3(NQV / 64, B_ * S_ / 128), dim3(256), 0, stream>>>(
      xb, wT, bqk, gamma, beta, bv, qb, kb, vb);
  k_transpose_v<<<dim3(DV / 32, S_ / 32, B_), dim3(32, 8), 0, stream>>>(vb, vT);
  k_gemm_sim<<<dim3(S_ / 64, S_ / 128, B_), dim3(256), 0, stream>>>(qb, kb, bias_n, attn);
  k_gemm_out<<<dim3(DV / 64, 64), dim3(256), 0, stream>>>(attn, vT, out);
}